// Round 3
// baseline (1047.780 us; speedup 1.0000x reference)
//
#include <hip/hip_runtime.h>
#include <hip/hip_fp16.h>

#define NN 100000
#define NE 3200000
#define FIN 300
#define HID 16
#define NC 10

#define NPB 128                 // nodes per bucket
#define NB 782                  // ceil(NN / NPB)
#define NSEG 512                // edge segments for histogram
#define EPS (NE / NSEG)         // 6250 edges per segment

// ---- phase 1: per-segment histogram over buckets (no global atomics) -------

__global__ void k_hist(const int* __restrict__ col, int* __restrict__ hist) {
    __shared__ int bins[NB];
    int seg = blockIdx.x, tid = threadIdx.x;
    for (int i = tid; i < NB; i += 256) bins[i] = 0;
    __syncthreads();
    int base = seg * EPS;
    for (int k = tid; k < EPS; k += 256)
        atomicAdd(&bins[col[base + k] >> 7], 1);
    __syncthreads();
    for (int i = tid; i < NB; i += 256) hist[seg * NB + i] = bins[i];
}

// ---- phase 2a: exclusive scan over segments, per bucket (coalesced) --------

__global__ void k_scanSeg(int* __restrict__ hist, int* __restrict__ bstart) {
    int bin = blockIdx.x * blockDim.x + threadIdx.x;
    if (bin >= NB) return;
    int run = 0;
    #pragma unroll 8
    for (int seg = 0; seg < NSEG; ++seg) {
        int idx = seg * NB + bin;
        int v = hist[idx];
        hist[idx] = run;
        run += v;
    }
    bstart[bin] = run;   // bucket total (scanned next)
}

// ---- phase 2b: exclusive scan over buckets (single WG) ---------------------

__global__ void k_scanBkt(int* __restrict__ bstart) {
    __shared__ int lds[1024];
    int t = threadIdx.x;
    int v = (t < NB) ? bstart[t] : 0;
    lds[t] = v; __syncthreads();
    for (int off = 1; off < 1024; off <<= 1) {
        int add = (t >= off) ? lds[t - off] : 0;
        __syncthreads();
        lds[t] += add;
        __syncthreads();
    }
    if (t <= NB) bstart[t] = lds[t] - v;   // exclusive; bstart[NB] = NE
}

// ---- phase 3: scatter edges into buckets (LDS cursors only) ----------------
// packed = row | (col_local << 17); weight stored as fp16.

__global__ void k_scatter(const int* __restrict__ row, const int* __restrict__ col,
                          const float* __restrict__ w, const int* __restrict__ hist,
                          const int* __restrict__ bstart, int* __restrict__ bkt_packed,
                          __half* __restrict__ bkt_w) {
    __shared__ int cur[NB];
    int seg = blockIdx.x, tid = threadIdx.x;
    for (int i = tid; i < NB; i += 256) cur[i] = bstart[i] + hist[seg * NB + i];
    __syncthreads();
    int base = seg * EPS;
    for (int k = tid; k < EPS; k += 256) {
        int e = base + k;
        int r = row[e], c = col[e];
        int bin = c >> 7;
        int pos = atomicAdd(&cur[bin], 1);
        bkt_packed[pos] = r | ((c & 127) << 17);
        bkt_w[pos] = __float2half(w[e]);
    }
}

// ---- phase 4: weighted in-degree per bucket -> dinv (no global atomics) ----

__global__ void k_deg(const int* __restrict__ bstart, const int* __restrict__ bkt_packed,
                      const __half* __restrict__ bkt_w, float* __restrict__ dinv) {
    __shared__ float ldeg[NPB];
    int b = blockIdx.x, tid = threadIdx.x;
    if (tid < NPB) ldeg[tid] = 1.0f;   // self-loop
    __syncthreads();
    int s = bstart[b], e = bstart[b + 1];
    for (int k = s + tid; k < e; k += 256)
        atomicAdd(&ldeg[bkt_packed[k] >> 17], __half2float(bkt_w[k]));
    __syncthreads();
    if (tid < NPB) {
        int node = b * NPB + tid;
        if (node < NN) dinv[node] = rsqrtf(ldeg[tid]);
    }
}

// ---- x @ W1 : [NN,300] x [300,16] ------------------------------------------

__global__ void k_xw(const float* __restrict__ x, const float* __restrict__ W1,
                     float* __restrict__ xw) {
    __shared__ float w1s[FIN * HID];
    for (int i = threadIdx.x; i < FIN * HID; i += blockDim.x) w1s[i] = W1[i];
    __syncthreads();
    long t = (long)blockIdx.x * blockDim.x + threadIdx.x;
    int node = (int)(t >> 4), c = (int)(t & 15);
    if (node >= NN) return;
    const float4* xr = (const float4*)(x + (long)node * FIN);  // 300 = 75 * 4
    float acc = 0.f;
    #pragma unroll 5
    for (int q = 0; q < FIN / 4; ++q) {
        float4 f = xr[q];
        int k = 4 * q;
        acc = fmaf(f.x, w1s[(k + 0) * HID + c], acc);
        acc = fmaf(f.y, w1s[(k + 1) * HID + c], acc);
        acc = fmaf(f.z, w1s[(k + 2) * HID + c], acc);
        acc = fmaf(f.w, w1s[(k + 3) * HID + c], acc);
    }
    xw[node * HID + c] = acc;
}

// ---- layer 1: per-bucket LDS-tile aggregation, fused b1/relu/@W2 -----------

__global__ void k_agg1(const int* __restrict__ bstart, const int* __restrict__ bkt_packed,
                       const __half* __restrict__ bkt_w, const float* __restrict__ xw,
                       const float* __restrict__ dinv, const float* __restrict__ b1,
                       const float* __restrict__ W2, float* __restrict__ hw2) {
    __shared__ float tile[NPB * 17];     // stride 17 breaks bank conflicts
    __shared__ float w2s[HID * NC];
    __shared__ float b1s[HID];
    int b = blockIdx.x, tid = threadIdx.x;
    for (int i = tid; i < NPB * 17; i += 256) tile[i] = 0.f;
    if (tid < HID * NC) w2s[tid] = W2[tid];
    if (tid < HID) b1s[tid] = b1[tid];
    __syncthreads();
    int g = tid >> 4, j = tid & 15;
    int s = bstart[b], e = bstart[b + 1];
    for (int k = s + g; k < e; k += 16) {
        int p = bkt_packed[k];
        int r = p & 0x1FFFF, cl = p >> 17;
        float a = dinv[r] * __half2float(bkt_w[k]);
        atomicAdd(&tile[cl * 17 + j], a * xw[r * HID + j]);
    }
    __syncthreads();
    if (tid < NPB) {
        int node = b * NPB + tid;
        if (node < NN) {
            float dc = dinv[node], d2 = dc * dc;
            float h[HID];
            #pragma unroll
            for (int c = 0; c < HID; ++c) {
                float v = fmaf(dc, tile[tid * 17 + c], d2 * xw[node * HID + c]) + b1s[c];
                h[c] = fmaxf(v, 0.f);
            }
            float acc[NC];
            #pragma unroll
            for (int c = 0; c < NC; ++c) acc[c] = 0.f;
            #pragma unroll
            for (int k2 = 0; k2 < HID; ++k2)
                #pragma unroll
                for (int c = 0; c < NC; ++c) acc[c] = fmaf(h[k2], w2s[k2 * NC + c], acc[c]);
            float* o = hw2 + (long)node * NC;
            #pragma unroll
            for (int c = 0; c < NC; ++c) o[c] = acc[c];
        }
    }
}

// ---- layer 2: per-bucket LDS-tile aggregation, fused b2/log_softmax --------

__global__ void k_agg2(const int* __restrict__ bstart, const int* __restrict__ bkt_packed,
                       const __half* __restrict__ bkt_w, const float* __restrict__ hw2,
                       const float* __restrict__ dinv, const float* __restrict__ b2,
                       float* __restrict__ out) {
    __shared__ float tile[NPB * 11];
    __shared__ float b2s[NC];
    int b = blockIdx.x, tid = threadIdx.x;
    for (int i = tid; i < NPB * 11; i += 256) tile[i] = 0.f;
    if (tid < NC) b2s[tid] = b2[tid];
    __syncthreads();
    int g = tid >> 4, j = tid & 15;
    int s = bstart[b], e = bstart[b + 1];
    for (int k = s + g; k < e; k += 16) {
        int p = bkt_packed[k];
        int r = p & 0x1FFFF, cl = p >> 17;
        float a = dinv[r] * __half2float(bkt_w[k]);
        if (j < NC) atomicAdd(&tile[cl * 11 + j], a * hw2[r * NC + j]);
    }
    __syncthreads();
    if (tid < NPB) {
        int node = b * NPB + tid;
        if (node < NN) {
            float dc = dinv[node], d2 = dc * dc;
            float v[NC], m = -1e30f;
            #pragma unroll
            for (int c = 0; c < NC; ++c) {
                v[c] = fmaf(dc, tile[tid * 11 + c], d2 * hw2[node * NC + c]) + b2s[c];
                m = fmaxf(m, v[c]);
            }
            float ssum = 0.f;
            #pragma unroll
            for (int c = 0; c < NC; ++c) ssum += __expf(v[c] - m);
            float ls = __logf(ssum);
            float* o = out + (long)node * NC;
            #pragma unroll
            for (int c = 0; c < NC; ++c) o[c] = v[c] - m - ls;
        }
    }
}

// ---- launch -----------------------------------------------------------------

extern "C" void kernel_launch(void* const* d_in, const int* in_sizes, int n_in,
                              void* d_out, int out_size, void* d_ws, size_t ws_size,
                              hipStream_t stream) {
    const float* x  = (const float*)d_in[0];
    const int*   ei = (const int*)d_in[1];     // [2, E] row-major (int32)
    const float* ew = (const float*)d_in[2];
    const float* W1 = (const float*)d_in[3];
    const float* b1 = (const float*)d_in[4];
    const float* W2 = (const float*)d_in[5];
    const float* b2 = (const float*)d_in[6];
    float* out = (float*)d_out;

    const int* row = ei;
    const int* col = ei + NE;

    // workspace layout (4-byte words); everything is fully written before read
    int*    hist       = (int*)d_ws;                   // NSEG*NB
    int*    bstart     = hist + NSEG * NB;             // NB+1
    float*  dinv       = (float*)(bstart + NB + 1);    // NN
    int*    bkt_packed = (int*)(dinv + NN);            // NE
    __half* bkt_w      = (__half*)(bkt_packed + NE);   // NE halves
    float*  xw         = (float*)(bkt_w + NE);         // NN*HID
    float*  hw2        = xw + (size_t)NN * HID;        // NN*NC
    // total: 400384 + 783 + 100000 + 3200000 + 1600000 + 1600000 + 1000000
    //      = 7,901,167 words = 31.6 MB

    k_hist<<<NSEG, 256, 0, stream>>>(col, hist);
    k_scanSeg<<<(NB + 255) / 256, 256, 0, stream>>>(hist, bstart);
    k_scanBkt<<<1, 1024, 0, stream>>>(bstart);
    k_scatter<<<NSEG, 256, 0, stream>>>(row, col, ew, hist, bstart, bkt_packed, bkt_w);
    k_deg<<<NB, 256, 0, stream>>>(bstart, bkt_packed, bkt_w, dinv);

    k_xw<<<(int)(((long)NN * 16 + 255) / 256), 256, 0, stream>>>(x, W1, xw);
    k_agg1<<<NB, 256, 0, stream>>>(bstart, bkt_packed, bkt_w, xw, dinv, b1, W2, hw2);
    k_agg2<<<NB, 256, 0, stream>>>(bstart, bkt_packed, bkt_w, hw2, dinv, b2, out);
}

// Round 4
// 554.377 us; speedup vs baseline: 1.8900x; 1.8900x over previous
//
#include <hip/hip_runtime.h>
#include <hip/hip_fp16.h>

#define NN 100000
#define NE 3200000
#define FIN 300
#define HID 16
#define NC 10

#define NPB 128                 // nodes per bucket
#define NB 782                  // ceil(NN / NPB)
#define NSEG 512                // edge segments for histogram
#define EPS (NE / NSEG)         // 6250 edges per segment
#define CAP 8192                // max bucket size staged in LDS (mean 4096, sd 64)

// ---- phase 1: per-segment histogram over buckets (no global atomics) -------

__global__ void k_hist(const int* __restrict__ col, int* __restrict__ hist) {
    __shared__ int bins[NB];
    int seg = blockIdx.x, tid = threadIdx.x;
    for (int i = tid; i < NB; i += 256) bins[i] = 0;
    __syncthreads();
    int base = seg * EPS;
    for (int k = tid; k < EPS; k += 256)
        atomicAdd(&bins[col[base + k] >> 7], 1);
    __syncthreads();
    for (int i = tid; i < NB; i += 256) hist[seg * NB + i] = bins[i];
}

// ---- phase 2a: exclusive scan over segments, per bucket (coalesced) --------

__global__ void k_scanSeg(int* __restrict__ hist, int* __restrict__ bstart) {
    int bin = blockIdx.x * blockDim.x + threadIdx.x;
    if (bin >= NB) return;
    int run = 0;
    #pragma unroll 8
    for (int seg = 0; seg < NSEG; ++seg) {
        int idx = seg * NB + bin;
        int v = hist[idx];
        hist[idx] = run;
        run += v;
    }
    bstart[bin] = run;   // bucket total (scanned next)
}

// ---- phase 2b: exclusive scan over buckets (single WG) ---------------------

__global__ void k_scanBkt(int* __restrict__ bstart) {
    __shared__ int lds[1024];
    int t = threadIdx.x;
    int v = (t < NB) ? bstart[t] : 0;
    lds[t] = v; __syncthreads();
    for (int off = 1; off < 1024; off <<= 1) {
        int add = (t >= off) ? lds[t - off] : 0;
        __syncthreads();
        lds[t] += add;
        __syncthreads();
    }
    if (t <= NB) bstart[t] = lds[t] - v;   // exclusive; bstart[NB] = NE
}

// ---- phase 3: scatter edges into buckets (LDS cursors only) ----------------
// packed = row | (col_local << 17); weight stored as fp16.

__global__ void k_scatter(const int* __restrict__ row, const int* __restrict__ col,
                          const float* __restrict__ w, const int* __restrict__ hist,
                          const int* __restrict__ bstart, int* __restrict__ bkt_packed,
                          __half* __restrict__ bkt_w) {
    __shared__ int cur[NB];
    int seg = blockIdx.x, tid = threadIdx.x;
    for (int i = tid; i < NB; i += 256) cur[i] = bstart[i] + hist[seg * NB + i];
    __syncthreads();
    int base = seg * EPS;
    for (int k = tid; k < EPS; k += 256) {
        int e = base + k;
        int r = row[e], c = col[e];
        int bin = c >> 7;
        int pos = atomicAdd(&cur[bin], 1);
        bkt_packed[pos] = r | ((c & 127) << 17);
        bkt_w[pos] = __float2half(w[e]);
    }
}

// ---- phase 4: per-bucket refine to full node-sorted order (in place) -------
// Also computes weighted degree -> dinv and per-node segment starts ns.

__global__ void k_refine(const int* __restrict__ bstart, int* __restrict__ bkt_packed,
                         __half* __restrict__ bkt_w, float* __restrict__ dinv,
                         int* __restrict__ ns) {
    __shared__ int cnt[NPB];
    __shared__ float wdeg[NPB];
    __shared__ int cur[NPB];
    __shared__ int epk[CAP];
    __shared__ __half ew[CAP];
    int b = blockIdx.x, tid = threadIdx.x;
    int s = bstart[b], e = bstart[b + 1];
    int size = min(e - s, CAP);       // CAP is 64-sigma above mean; never clips here
    if (tid < NPB) { cnt[tid] = 0; wdeg[tid] = 1.0f; }   // self-loop weight
    __syncthreads();
    for (int k = tid; k < size; k += 256) {
        int p = bkt_packed[s + k];
        __half w = bkt_w[s + k];
        epk[k] = p; ew[k] = w;
        atomicAdd(&cnt[p >> 17], 1);
        atomicAdd(&wdeg[p >> 17], __half2float(w));
    }
    __syncthreads();
    int v = (tid < NPB) ? cnt[tid] : 0;
    for (int off = 1; off < NPB; off <<= 1) {
        int add = (tid >= off && tid < NPB) ? cnt[tid - off] : 0;
        __syncthreads();
        if (tid < NPB) cnt[tid] += add;
        __syncthreads();
    }
    if (tid < NPB) {
        int excl = cnt[tid] - v;
        cur[tid] = excl;
        int node = b * NPB + tid;
        if (node < NN) {
            ns[node] = s + excl;
            dinv[node] = rsqrtf(wdeg[tid]);
        }
    }
    if (b == NB - 1 && tid == 0) ns[NN] = e;
    __syncthreads();
    for (int k = tid; k < size; k += 256) {
        int p = epk[k];
        int pos = s + atomicAdd(&cur[p >> 17], 1);
        bkt_packed[pos] = p & 0x1FFFF;   // plain source-row id now
        bkt_w[pos] = ew[k];
    }
}

// ---- x @ W1, pre-scaled by dinv, fp16 out: xws[i] = dinv[i] * (x[i] @ W1) --

__global__ void k_xw(const float* __restrict__ x, const float* __restrict__ W1,
                     const float* __restrict__ dinv, __half* __restrict__ xws) {
    __shared__ float w1s[FIN * HID];
    for (int i = threadIdx.x; i < FIN * HID; i += blockDim.x) w1s[i] = W1[i];
    __syncthreads();
    int t = blockIdx.x * 256 + threadIdx.x;
    int node = t >> 4, c = t & 15;
    if (node >= NN) return;
    const float4* xr = (const float4*)(x + (long)node * FIN);  // 300 = 75 * 4
    float acc = 0.f;
    #pragma unroll 5
    for (int q = 0; q < FIN / 4; ++q) {
        float4 f = xr[q];
        int k = 4 * q;
        acc = fmaf(f.x, w1s[(k + 0) * HID + c], acc);
        acc = fmaf(f.y, w1s[(k + 1) * HID + c], acc);
        acc = fmaf(f.z, w1s[(k + 2) * HID + c], acc);
        acc = fmaf(f.w, w1s[(k + 3) * HID + c], acc);
    }
    xws[node * HID + c] = __float2half(dinv[node] * acc);
}

// ---- layer 1 pull-gather (no atomics), fused b1/relu/@W2 -------------------
// h = relu(dinv[i]*(sum_e w_e*xws[r_e] + xws[i]) + b1); hw2s[i] = dinv[i]*(h@W2)

__global__ void k_gather1(const int* __restrict__ ns, const int* __restrict__ srow,
                          const __half* __restrict__ w16, const __half* __restrict__ xws,
                          const float* __restrict__ dinv, const float* __restrict__ b1,
                          const float* __restrict__ W2, __half* __restrict__ hw2s) {
    __shared__ float w2s[HID * NC];
    __shared__ float b1s[HID];
    if (threadIdx.x < HID * NC) w2s[threadIdx.x] = W2[threadIdx.x];
    if (threadIdx.x < HID) b1s[threadIdx.x] = b1[threadIdx.x];
    __syncthreads();
    int t = blockIdx.x * 256 + threadIdx.x;
    int i = t >> 4, c = t & 15;
    int s = ns[i], e = ns[i + 1];
    float acc = 0.f;
    int k = s;
    for (; k + 4 <= e; k += 4) {
        int r0 = srow[k], r1 = srow[k + 1], r2 = srow[k + 2], r3 = srow[k + 3];
        float f0 = __half2float(w16[k]),     f1 = __half2float(w16[k + 1]);
        float f2 = __half2float(w16[k + 2]), f3 = __half2float(w16[k + 3]);
        acc = fmaf(f0, __half2float(xws[r0 * HID + c]), acc);
        acc = fmaf(f1, __half2float(xws[r1 * HID + c]), acc);
        acc = fmaf(f2, __half2float(xws[r2 * HID + c]), acc);
        acc = fmaf(f3, __half2float(xws[r3 * HID + c]), acc);
    }
    for (; k < e; ++k)
        acc = fmaf(__half2float(w16[k]), __half2float(xws[srow[k] * HID + c]), acc);
    acc += __half2float(xws[i * HID + c]);   // self loop
    float dc = dinv[i];
    float h = fmaxf(fmaf(dc, acc, b1s[c]), 0.f);
    float acc2 = 0.f;
    int jj = (c < NC) ? c : 0;
    #pragma unroll
    for (int k2 = 0; k2 < HID; ++k2) {
        float hk = __shfl(h, k2, HID);
        acc2 = fmaf(hk, w2s[k2 * NC + jj], acc2);
    }
    if (c < NC) hw2s[i * NC + c] = __float2half(dc * acc2);
}

// ---- layer 2 pull-gather, fused b2/log_softmax -> out ----------------------

__global__ void k_gather2(const int* __restrict__ ns, const int* __restrict__ srow,
                          const __half* __restrict__ w16, const __half* __restrict__ hw2s,
                          const float* __restrict__ dinv, const float* __restrict__ b2,
                          float* __restrict__ out) {
    int t = blockIdx.x * 256 + threadIdx.x;
    int i = t >> 4, j = t & 15;
    int s = ns[i], e = ns[i + 1];
    float v;
    if (j < NC) {
        float acc = 0.f;
        int k = s;
        for (; k + 4 <= e; k += 4) {
            int r0 = srow[k], r1 = srow[k + 1], r2 = srow[k + 2], r3 = srow[k + 3];
            float f0 = __half2float(w16[k]),     f1 = __half2float(w16[k + 1]);
            float f2 = __half2float(w16[k + 2]), f3 = __half2float(w16[k + 3]);
            acc = fmaf(f0, __half2float(hw2s[r0 * NC + j]), acc);
            acc = fmaf(f1, __half2float(hw2s[r1 * NC + j]), acc);
            acc = fmaf(f2, __half2float(hw2s[r2 * NC + j]), acc);
            acc = fmaf(f3, __half2float(hw2s[r3 * NC + j]), acc);
        }
        for (; k < e; ++k)
            acc = fmaf(__half2float(w16[k]), __half2float(hw2s[srow[k] * NC + j]), acc);
        acc += __half2float(hw2s[i * NC + j]);   // self loop
        v = fmaf(dinv[i], acc, b2[j]);
    } else {
        v = -1e30f;
    }
    float m = v;
    #pragma unroll
    for (int mask = 8; mask > 0; mask >>= 1) m = fmaxf(m, __shfl_xor(m, mask, HID));
    float ev = (j < NC) ? __expf(v - m) : 0.f;
    float ssum = ev;
    #pragma unroll
    for (int mask = 8; mask > 0; mask >>= 1) ssum += __shfl_xor(ssum, mask, HID);
    if (j < NC) out[(long)i * NC + j] = v - m - __logf(ssum);
}

// ---- launch -----------------------------------------------------------------

extern "C" void kernel_launch(void* const* d_in, const int* in_sizes, int n_in,
                              void* d_out, int out_size, void* d_ws, size_t ws_size,
                              hipStream_t stream) {
    const float* x  = (const float*)d_in[0];
    const int*   ei = (const int*)d_in[1];     // [2, E] row-major (int32)
    const float* ew = (const float*)d_in[2];
    const float* W1 = (const float*)d_in[3];
    const float* b1 = (const float*)d_in[4];
    const float* W2 = (const float*)d_in[5];
    const float* b2 = (const float*)d_in[6];
    float* out = (float*)d_out;

    const int* row = ei;
    const int* col = ei + NE;

    // workspace layout (4-byte words); every word written before read
    int*    hist       = (int*)d_ws;                   // NSEG*NB     = 400384
    int*    bstart     = hist + NSEG * NB;             // NB+1        = 783
    float*  dinv       = (float*)(bstart + NB + 1);    // NN          = 100000
    int*    ns         = (int*)(dinv + NN);            // NN+1        = 100001
    int*    bkt_packed = ns + NN + 1;                  // NE          = 3200000
    __half* bkt_w      = (__half*)(bkt_packed + NE);   // NE halves   = 1600000 w
    __half* xws        = bkt_w + NE;                   // NN*HID h    = 800000 w
    __half* hw2s       = xws + (size_t)NN * HID;       // NN*NC h     = 500000 w
    // total = 6,701,168 words = 26.8 MB

    k_hist<<<NSEG, 256, 0, stream>>>(col, hist);
    k_scanSeg<<<(NB + 255) / 256, 256, 0, stream>>>(hist, bstart);
    k_scanBkt<<<1, 1024, 0, stream>>>(bstart);
    k_scatter<<<NSEG, 256, 0, stream>>>(row, col, ew, hist, bstart, bkt_packed, bkt_w);
    k_refine<<<NB, 256, 0, stream>>>(bstart, bkt_packed, bkt_w, dinv, ns);

    k_xw<<<(NN * 16) / 256, 256, 0, stream>>>(x, W1, dinv, xws);
    k_gather1<<<(NN * 16) / 256, 256, 0, stream>>>(ns, bkt_packed, bkt_w, xws, dinv, b1, W2, hw2s);
    k_gather2<<<(NN * 16) / 256, 256, 0, stream>>>(ns, bkt_packed, bkt_w, hw2s, dinv, b2, out);
}

// Round 5
// 449.562 us; speedup vs baseline: 2.3307x; 1.2332x over previous
//
#include <hip/hip_runtime.h>
#include <hip/hip_fp16.h>

#define NN 100000
#define NE 3200000
#define FIN 300
#define HID 16
#define NC 10

#define NPB 64                  // nodes per bucket
#define NB 1563                 // ceil(NN / NPB)
#define NSEG 512                // edge segments
#define EPS (NE / NSEG)         // 6250 edges per segment
#define NCH 8                   // chunks for the seg-scan
#define SEGPC (NSEG / NCH)      // 64 segs per chunk
#define CAP 4096                // max bucket size (mean 2048, sd ~45)

__device__ __forceinline__ float h2f_lo(int y) {
    __half_raw hr; hr.x = (unsigned short)(y & 0xFFFF);
    __half h; *(__half_raw*)&h = hr;
    return __half2float(h);
}
__device__ __forceinline__ int f2h_us(float f) {
    __half h = __float2half(f);
    return (int)(*(__half_raw*)&h).x;
}

// ---- phase 1: per-segment histogram over buckets ---------------------------

__global__ void k_hist(const int* __restrict__ col, int* __restrict__ hist) {
    __shared__ int bins[NB];
    int seg = blockIdx.x, tid = threadIdx.x;
    for (int i = tid; i < NB; i += 256) bins[i] = 0;
    __syncthreads();
    int base = seg * EPS;
    for (int k = tid; k < EPS; k += 256) atomicAdd(&bins[col[base + k] >> 6], 1);
    __syncthreads();
    for (int i = tid; i < NB; i += 256) hist[seg * NB + i] = bins[i];
}

// ---- phase 2: parallel scan of hist over segs ------------------------------

__global__ void k_psumA(const int* __restrict__ hist, int* __restrict__ psum) {
    int bin = blockIdx.x * 256 + threadIdx.x;
    int ch = blockIdx.y;
    if (bin >= NB) return;
    int s = 0;
    for (int seg = ch * SEGPC; seg < (ch + 1) * SEGPC; ++seg) s += hist[seg * NB + bin];
    psum[ch * NB + bin] = s;
}

__global__ void k_psumB(int* __restrict__ psum, int* __restrict__ bstart) {
    int bin = blockIdx.x * 256 + threadIdx.x;
    if (bin >= NB) return;
    int run = 0;
    #pragma unroll
    for (int ch = 0; ch < NCH; ++ch) {
        int v = psum[ch * NB + bin];
        psum[ch * NB + bin] = run;
        run += v;
    }
    bstart[bin] = run;
}

__global__ void k_scanBkt(int* __restrict__ bstart) {
    __shared__ int lsum[256];
    int t = threadIdx.x;
    const int M = (NB + 255) / 256;   // 7
    int base = t * M;
    int s = 0;
    for (int q = 0; q < M; ++q) { int i = base + q; if (i < NB) s += bstart[i]; }
    lsum[t] = s; __syncthreads();
    for (int off = 1; off < 256; off <<= 1) {
        int add = (t >= off) ? lsum[t - off] : 0;
        __syncthreads(); lsum[t] += add; __syncthreads();
    }
    int run = (t > 0) ? lsum[t - 1] : 0;
    for (int q = 0; q < M; ++q) {
        int i = base + q;
        if (i < NB) { int v = bstart[i]; bstart[i] = run; run += v; }
    }
    if (t == 255) bstart[NB] = run;   // = NE
}

__global__ void k_applyC(int* __restrict__ hist, const int* __restrict__ psum,
                         const int* __restrict__ bstart) {
    int bin = blockIdx.x * 256 + threadIdx.x;
    int ch = blockIdx.y;
    if (bin >= NB) return;
    int run = bstart[bin] + psum[ch * NB + bin];
    for (int seg = ch * SEGPC; seg < (ch + 1) * SEGPC; ++seg) {
        int idx = seg * NB + bin;
        int v = hist[idx];
        hist[idx] = run;
        run += v;
    }
}

// ---- phase 3: LDS-sorted scatter, coalesced int2 writes --------------------
// record: .x = row | (col&63)<<17 ; .y = w_half | bin<<16 (bin bits scrubbed later)

__launch_bounds__(256)
__global__ void k_scatter(const int* __restrict__ row, const int* __restrict__ col,
                          const float* __restrict__ w, const int* __restrict__ hist,
                          int2* __restrict__ bkt) {
    __shared__ int bins[NB];
    __shared__ int cur[NB];
    __shared__ int lsum[256];
    __shared__ int2 sdata[EPS];
    int seg = blockIdx.x, tid = threadIdx.x;
    for (int i = tid; i < NB; i += 256) bins[i] = 0;
    __syncthreads();
    int base = seg * EPS;
    for (int k = tid; k < EPS; k += 256) atomicAdd(&bins[col[base + k] >> 6], 1);
    __syncthreads();
    // block exclusive scan of bins
    const int M = (NB + 255) / 256;
    int lbase = tid * M;
    int s = 0;
    for (int q = 0; q < M; ++q) { int i = lbase + q; if (i < NB) s += bins[i]; }
    lsum[tid] = s; __syncthreads();
    for (int off = 1; off < 256; off <<= 1) {
        int add = (tid >= off) ? lsum[tid - off] : 0;
        __syncthreads(); lsum[tid] += add; __syncthreads();
    }
    int run = (tid > 0) ? lsum[tid - 1] : 0;
    for (int q = 0; q < M; ++q) {
        int i = lbase + q;
        if (i < NB) { int v = bins[i]; bins[i] = run; cur[i] = run; run += v; }
    }
    __syncthreads();
    // place into LDS sorted by bin
    for (int k = tid; k < EPS; k += 256) {
        int e = base + k;
        int r = row[e], c = col[e];
        int bin = c >> 6;
        int pos = atomicAdd(&cur[bin], 1);
        sdata[pos] = make_int2(r | ((c & 63) << 17), f2h_us(w[e]) | (bin << 16));
    }
    __syncthreads();
    // bins[bin] := global_start(seg,bin) - lds_start(bin)
    for (int i = tid; i < NB; i += 256) bins[i] = hist[seg * NB + i] - bins[i];
    __syncthreads();
    for (int j = tid; j < EPS; j += 256) {
        int2 d = sdata[j];
        int bin = ((unsigned)d.y) >> 16;
        bkt[bins[bin] + j] = d;
    }
}

// ---- phase 4: per-bucket refine to node order (coalesced write-back) -------

__launch_bounds__(256)
__global__ void k_refine(const int* __restrict__ bstart, int2* __restrict__ bkt,
                         float* __restrict__ dinv, int* __restrict__ ns) {
    __shared__ int cnt[NPB];
    __shared__ int cur[NPB];
    __shared__ float wdeg[NPB];
    __shared__ int2 sorted[CAP];
    int b = blockIdx.x, tid = threadIdx.x;
    int s = bstart[b], e = bstart[b + 1];
    int size = e - s; if (size > CAP) size = CAP;   // 45-sigma guard, never hit
    if (tid < NPB) { cnt[tid] = 0; wdeg[tid] = 1.0f; }   // self-loop weight
    __syncthreads();
    for (int k = tid; k < size; k += 256) {
        int2 d = bkt[s + k];
        int cl = (d.x >> 17) & 63;
        atomicAdd(&cnt[cl], 1);
        atomicAdd(&wdeg[cl], h2f_lo(d.y));
    }
    __syncthreads();
    int v = (tid < NPB) ? cnt[tid] : 0;
    for (int off = 1; off < NPB; off <<= 1) {
        int add = (tid >= off && tid < NPB) ? cnt[tid - off] : 0;
        __syncthreads();
        if (tid < NPB) cnt[tid] += add;
        __syncthreads();
    }
    if (tid < NPB) {
        int excl = cnt[tid] - v;
        cur[tid] = excl;
        int node = b * NPB + tid;
        if (node < NN) { ns[node] = s + excl; dinv[node] = rsqrtf(wdeg[tid]); }
    }
    if (b == NB - 1 && tid == 0) ns[NN] = e;
    __syncthreads();
    for (int k = tid; k < size; k += 256) {
        int2 d = bkt[s + k];
        int cl = (d.x >> 17) & 63;
        int pos = atomicAdd(&cur[cl], 1);
        sorted[pos] = make_int2(d.x & 0x1FFFF, d.y & 0xFFFF);
    }
    __syncthreads();
    for (int k = tid; k < size; k += 256) bkt[s + k] = sorted[k];
}

// ---- x @ W1, pre-scaled by dinv, fp16 out; 4 nodes x 4 cols per thread -----

__launch_bounds__(256)
__global__ void k_xw(const float* __restrict__ x, const float* __restrict__ W1,
                     const float* __restrict__ dinv, int2* __restrict__ xws) {
    __shared__ float w1s[FIN * HID];
    for (int i = threadIdx.x; i < FIN * HID; i += 256) w1s[i] = W1[i];
    __syncthreads();
    int t = blockIdx.x * 256 + threadIdx.x;
    int nq = t >> 2, cq = t & 3;
    int n0 = nq * 4;
    if (n0 >= NN) return;
    float acc[4][4];
    #pragma unroll
    for (int i = 0; i < 4; ++i)
        #pragma unroll
        for (int j = 0; j < 4; ++j) acc[i][j] = 0.f;
    const float* xp = x + (long)n0 * FIN;
    for (int q = 0; q < FIN / 4; ++q) {
        float xv[4][4], wv[4][4];
        #pragma unroll
        for (int i = 0; i < 4; ++i) {
            float4 f = *(const float4*)(xp + i * FIN + q * 4);
            xv[i][0] = f.x; xv[i][1] = f.y; xv[i][2] = f.z; xv[i][3] = f.w;
        }
        #pragma unroll
        for (int kk = 0; kk < 4; ++kk) {
            float4 f = *(const float4*)&w1s[(4 * q + kk) * HID + cq * 4];
            wv[kk][0] = f.x; wv[kk][1] = f.y; wv[kk][2] = f.z; wv[kk][3] = f.w;
        }
        #pragma unroll
        for (int i = 0; i < 4; ++i)
            #pragma unroll
            for (int kk = 0; kk < 4; ++kk)
                #pragma unroll
                for (int j = 0; j < 4; ++j)
                    acc[i][j] = fmaf(xv[i][kk], wv[kk][j], acc[i][j]);
    }
    #pragma unroll
    for (int i = 0; i < 4; ++i) {
        float di = dinv[n0 + i];
        int2 o;
        o.x = f2h_us(di * acc[i][0]) | (f2h_us(di * acc[i][1]) << 16);
        o.y = f2h_us(di * acc[i][2]) | (f2h_us(di * acc[i][3]) << 16);
        xws[(long)(n0 + i) * 4 + cq] = o;
    }
}

// ---- layer 1 pull-gather, fused b1/relu/@W2 --------------------------------

__global__ void k_gather1(const int* __restrict__ ns, const int2* __restrict__ bkt,
                          const unsigned short* __restrict__ xwsh,
                          const float* __restrict__ dinv, const float* __restrict__ b1,
                          const float* __restrict__ W2, unsigned short* __restrict__ hw2s) {
    __shared__ float w2s[HID * NC];
    __shared__ float b1s[HID];
    if (threadIdx.x < HID * NC) w2s[threadIdx.x] = W2[threadIdx.x];
    if (threadIdx.x < HID) b1s[threadIdx.x] = b1[threadIdx.x];
    __syncthreads();
    int t = blockIdx.x * 256 + threadIdx.x;
    int i = t >> 4, c = t & 15;
    int s = ns[i], e = ns[i + 1];
    float acc = 0.f;
    int k = s;
    for (; k + 4 <= e; k += 4) {
        int2 e0 = bkt[k], e1 = bkt[k + 1], e2 = bkt[k + 2], e3 = bkt[k + 3];
        __half_raw h0; h0.x = xwsh[e0.x * HID + c];
        __half_raw h1; h1.x = xwsh[e1.x * HID + c];
        __half_raw h2; h2.x = xwsh[e2.x * HID + c];
        __half_raw h3; h3.x = xwsh[e3.x * HID + c];
        acc = fmaf(h2f_lo(e0.y), __half2float(*(__half*)&h0), acc);
        acc = fmaf(h2f_lo(e1.y), __half2float(*(__half*)&h1), acc);
        acc = fmaf(h2f_lo(e2.y), __half2float(*(__half*)&h2), acc);
        acc = fmaf(h2f_lo(e3.y), __half2float(*(__half*)&h3), acc);
    }
    for (; k < e; ++k) {
        int2 e0 = bkt[k];
        __half_raw h0; h0.x = xwsh[e0.x * HID + c];
        acc = fmaf(h2f_lo(e0.y), __half2float(*(__half*)&h0), acc);
    }
    { __half_raw hs; hs.x = xwsh[i * HID + c]; acc += __half2float(*(__half*)&hs); }
    float dc = dinv[i];
    float h = fmaxf(fmaf(dc, acc, b1s[c]), 0.f);
    float acc2 = 0.f;
    int jj = (c < NC) ? c : 0;
    #pragma unroll
    for (int k2 = 0; k2 < HID; ++k2) {
        float hk = __shfl(h, k2, HID);
        acc2 = fmaf(hk, w2s[k2 * NC + jj], acc2);
    }
    if (c < NC) hw2s[i * NC + c] = (unsigned short)f2h_us(dc * acc2);
}

// ---- layer 2 pull-gather, fused b2/log_softmax -----------------------------

__global__ void k_gather2(const int* __restrict__ ns, const int2* __restrict__ bkt,
                          const unsigned short* __restrict__ hw2s,
                          const float* __restrict__ dinv, const float* __restrict__ b2,
                          float* __restrict__ out) {
    int t = blockIdx.x * 256 + threadIdx.x;
    int i = t >> 4, j = t & 15;
    int s = ns[i], e = ns[i + 1];
    float v;
    if (j < NC) {
        float acc = 0.f;
        int k = s;
        for (; k + 4 <= e; k += 4) {
            int2 e0 = bkt[k], e1 = bkt[k + 1], e2 = bkt[k + 2], e3 = bkt[k + 3];
            __half_raw h0; h0.x = hw2s[e0.x * NC + j];
            __half_raw h1; h1.x = hw2s[e1.x * NC + j];
            __half_raw h2; h2.x = hw2s[e2.x * NC + j];
            __half_raw h3; h3.x = hw2s[e3.x * NC + j];
            acc = fmaf(h2f_lo(e0.y), __half2float(*(__half*)&h0), acc);
            acc = fmaf(h2f_lo(e1.y), __half2float(*(__half*)&h1), acc);
            acc = fmaf(h2f_lo(e2.y), __half2float(*(__half*)&h2), acc);
            acc = fmaf(h2f_lo(e3.y), __half2float(*(__half*)&h3), acc);
        }
        for (; k < e; ++k) {
            int2 e0 = bkt[k];
            __half_raw h0; h0.x = hw2s[e0.x * NC + j];
            acc = fmaf(h2f_lo(e0.y), __half2float(*(__half*)&h0), acc);
        }
        { __half_raw hs; hs.x = hw2s[i * NC + j]; acc += __half2float(*(__half*)&hs); }
        v = fmaf(dinv[i], acc, b2[j]);
    } else {
        v = -1e30f;
    }
    float m = v;
    #pragma unroll
    for (int mask = 8; mask > 0; mask >>= 1) m = fmaxf(m, __shfl_xor(m, mask, HID));
    float ev = (j < NC) ? __expf(v - m) : 0.f;
    float ssum = ev;
    #pragma unroll
    for (int mask = 8; mask > 0; mask >>= 1) ssum += __shfl_xor(ssum, mask, HID);
    if (j < NC) out[(long)i * NC + j] = v - m - __logf(ssum);
}

// ---- launch -----------------------------------------------------------------

extern "C" void kernel_launch(void* const* d_in, const int* in_sizes, int n_in,
                              void* d_out, int out_size, void* d_ws, size_t ws_size,
                              hipStream_t stream) {
    const float* x  = (const float*)d_in[0];
    const int*   ei = (const int*)d_in[1];
    const float* ew = (const float*)d_in[2];
    const float* W1 = (const float*)d_in[3];
    const float* b1 = (const float*)d_in[4];
    const float* W2 = (const float*)d_in[5];
    const float* b2 = (const float*)d_in[6];
    float* out = (float*)d_out;

    const int* row = ei;
    const int* col = ei + NE;

    // workspace (words); xws overlays hist (dead after k_scatter)
    int*   hist   = (int*)d_ws;                    // NSEG*NB = 800,256
    int*   psum   = hist + NSEG * NB;              // NCH*NB  = 12,504
    int*   bstart = psum + NCH * NB;               // NB+1    = 1,564
    float* dinv   = (float*)(bstart + NB + 1);     // 100,000
    int*   ns     = (int*)(dinv + NN);             // 100,001
    size_t o = (size_t)(NSEG * NB) + NCH * NB + (NB + 1) + NN + (NN + 1);
    o = (o + 1) & ~(size_t)1;                      // 8B align for int2
    int2*  bkt    = (int2*)((int*)d_ws + o);       // NE int2 = 6,400,000 w
    unsigned short* hw2s = (unsigned short*)(bkt + NE);   // NN*NC halves = 500,000 w
    int2*  xws    = (int2*)hist;                   // NN*4 int2 = 800,000 w overlay
    // total ~= 7,914,326 words = 31.7 MB

    k_hist<<<NSEG, 256, 0, stream>>>(col, hist);
    k_psumA<<<dim3((NB + 255) / 256, NCH), 256, 0, stream>>>(hist, psum);
    k_psumB<<<(NB + 255) / 256, 256, 0, stream>>>(psum, bstart);
    k_scanBkt<<<1, 256, 0, stream>>>(bstart);
    k_applyC<<<dim3((NB + 255) / 256, NCH), 256, 0, stream>>>(hist, psum, bstart);
    k_scatter<<<NSEG, 256, 0, stream>>>(row, col, ew, hist, bkt);
    k_refine<<<NB, 256, 0, stream>>>(bstart, bkt, dinv, ns);

    k_xw<<<(NN + 255) / 256, 256, 0, stream>>>(x, W1, dinv, xws);
    k_gather1<<<(NN * 16) / 256, 256, 0, stream>>>(ns, bkt, (const unsigned short*)xws,
                                                   dinv, b1, W2, hw2s);
    k_gather2<<<(NN * 16) / 256, 256, 0, stream>>>(ns, bkt, hw2s, dinv, b2, out);
}